// Round 4
// baseline (314.222 us; speedup 1.0000x reference)
//
#include <hip/hip_runtime.h>
#include <hip/hip_bf16.h>

typedef __attribute__((ext_vector_type(8))) short bf16x8;
typedef __attribute__((ext_vector_type(4))) float f32x4;
typedef unsigned short ushort_t;

#define HID 2048
#define QKVN 6144
#define SEQ 2048
#define NH 16
#define HD 128
#define QB 128
#define KVB 64

#define GLOBAL_AS __attribute__((address_space(1)))
#define LDS_AS __attribute__((address_space(3)))

__device__ __forceinline__ void gload_lds16(const ushort_t* g, ushort_t* l) {
    __builtin_amdgcn_global_load_lds((const GLOBAL_AS unsigned int*)g,
                                     (LDS_AS unsigned int*)l, 16, 0, 0);
}

__device__ __forceinline__ ushort_t f2b(float f) {
    union { float f; unsigned int u; } x; x.f = f;
    unsigned int r = x.u + 0x7fffu + ((x.u >> 16) & 1u);  // RNE
    return (ushort_t)(r >> 16);
}

// ---------------- cast fp32 -> bf16 (vectorized) ----------------
__global__ __launch_bounds__(256) void castbf(const float* __restrict__ in,
                                              ushort_t* __restrict__ out, int n) {
    int i = (blockIdx.x * 256 + threadIdx.x) * 8;
    if (i >= n) return;
    float4 a = *(const float4*)(in + i);
    float4 b = *(const float4*)(in + i + 4);
    union { ushort_t u[8]; uint4 v; } r;
    r.u[0] = f2b(a.x); r.u[1] = f2b(a.y); r.u[2] = f2b(a.z); r.u[3] = f2b(a.w);
    r.u[4] = f2b(b.x); r.u[5] = f2b(b.y); r.u[6] = f2b(b.z); r.u[7] = f2b(b.w);
    *(uint4*)(out + i) = r.v;
}

// ------------- transpose + cast: fp32 K x N  ->  bf16 N x K -------------
__global__ __launch_bounds__(256) void transcast(const float* __restrict__ in,
                                                 ushort_t* __restrict__ out,
                                                 int Kd, int Nd) {
    __shared__ float tile[32][33];
    int tx = threadIdx.x & 31, ty = threadIdx.x >> 5;
    int n0 = blockIdx.x * 32, k0 = blockIdx.y * 32;
    for (int j = 0; j < 4; j++)
        tile[ty + 8 * j][tx] = in[(size_t)(k0 + ty + 8 * j) * Nd + n0 + tx];
    __syncthreads();
    for (int j = 0; j < 4; j++)
        out[(size_t)(n0 + ty + 8 * j) * Kd + k0 + tx] = f2b(tile[tx][ty + 8 * j]);
}

// ------------- transpose V region of qkv (bf16) -> vT[b][h][d][s] -------------
__global__ __launch_bounds__(256) void transV(const ushort_t* __restrict__ qkvb,
                                              ushort_t* __restrict__ vT) {
    __shared__ ushort_t tile[32][33];
    int tx = threadIdx.x & 31, ty = threadIdx.x >> 5;
    int s0 = blockIdx.x * 32, d0 = blockIdx.y * 32;
    int bh = blockIdx.z; int b = bh >> 4, h = bh & 15;
    for (int j = 0; j < 4; j++)
        tile[ty + 8 * j][tx] =
            qkvb[(size_t)(b * SEQ + s0 + ty + 8 * j) * QKVN + 2 * HID + h * HD + d0 + tx];
    __syncthreads();
    for (int j = 0; j < 4; j++)
        vT[((size_t)bh * HD + d0 + ty + 8 * j) * SEQ + s0 + tx] = tile[tx][ty + 8 * j];
}

// ------------- GEMM 256x256 deep-pipelined (T2+T3+T4+T5), BK=64, 8 waves -------------
// C(MxN,bf16) = A(MxK,bf16) * BT(NxK,bf16)^T. Distance-2 K-tile prefetch, vmcnt(8).
__global__ __launch_bounds__(512, 1) void gemm256(const ushort_t* __restrict__ A,
                                                  const ushort_t* __restrict__ BT,
                                                  ushort_t* __restrict__ C,
                                                  int M, int N, int K,
                                                  int scale_cols, float scale) {
    __shared__ __align__(16) ushort_t As[2][2][128 * 64];  // [buf][half][row*64+col]
    __shared__ __align__(16) ushort_t Bs[2][2][128 * 64];

    const int t = threadIdx.x;
    const int l = t & 63, w = t >> 6;
    const int wm = w >> 2, wn = w & 3;          // 2 x 4 waves
    const int lr = l & 15, lg = l >> 4;

    // XCD-aware bijective swizzle (nwg % 8 == 0)
    const int nwg = gridDim.x;
    const int cpx = nwg >> 3;
    const int sw = (blockIdx.x & 7) * cpx + (blockIdx.x >> 3);
    const int NTN = N / 256;
    const int m0 = (sw / NTN) * 256, n0 = (sw % NTN) * 256;

    const int NKT = K / 64;

    f32x4 acc[8][4] = {};

    // staging: chunk i = s*512+t; row = i>>3, slot = i&7; source col pre-swizzled
#define STAGE_TILE(kt, buf)                                                              \
    do {                                                                                 \
        const int k0_ = (kt) * 64;                                                       \
        _Pragma("unroll")                                                                \
        for (int s = 0; s < 2; s++) {                                                    \
            const int i_ = s * 512 + t;                                                  \
            const int row_ = i_ >> 3;                                                    \
            const int col_ = ((i_ & 7) ^ (row_ & 7)) << 3;                               \
            gload_lds16(A  + (size_t)(m0 + row_) * K + k0_ + col_,       &As[buf][0][i_ * 8]); \
            gload_lds16(A  + (size_t)(m0 + 128 + row_) * K + k0_ + col_, &As[buf][1][i_ * 8]); \
            gload_lds16(BT + (size_t)(n0 + row_) * K + k0_ + col_,       &Bs[buf][0][i_ * 8]); \
            gload_lds16(BT + (size_t)(n0 + 128 + row_) * K + k0_ + col_, &Bs[buf][1][i_ * 8]); \
        }                                                                                \
    } while (0)

    STAGE_TILE(0, 0);
    STAGE_TILE(1, 1);
    asm volatile("s_waitcnt vmcnt(8)" ::: "memory");  // tile 0 landed; tile 1 in flight
    __builtin_amdgcn_s_barrier();

    const int swz = (lr & 7) << 4;
    const int arow0 = lr * 128;                 // + mi*2048 bytes
    const int brow0 = ((wn & 1) * 64 + lr) * 128;  // + ni*2048 bytes

    for (int kt = 0; kt < NKT; kt++) {
        const int cur = kt & 1;
        const char* aB = (const char*)As[cur][wm];
        const char* bB = (const char*)Bs[cur][wn >> 1];

#pragma unroll
        for (int kk = 0; kk < 2; kk++) {
            bf16x8 bfr[4];
#pragma unroll
            for (int ni = 0; ni < 4; ni++)
                bfr[ni] = *(const bf16x8*)(bB + brow0 + ni * 2048 + ((((kk * 4 + lg) << 4)) ^ swz));
#pragma unroll
            for (int mh = 0; mh < 2; mh++) {
                bf16x8 af[4];
#pragma unroll
                for (int mi = 0; mi < 4; mi++)
                    af[mi] = *(const bf16x8*)(aB + arow0 + (mh * 4 + mi) * 2048 + ((((kk * 4 + lg) << 4)) ^ swz));
                __builtin_amdgcn_s_setprio(1);
#pragma unroll
                for (int mi = 0; mi < 4; mi++)
#pragma unroll
                    for (int ni = 0; ni < 4; ni++)
                        acc[mh * 4 + mi][ni] = __builtin_amdgcn_mfma_f32_16x16x32_bf16(
                            af[mi], bfr[ni], acc[mh * 4 + mi][ni], 0, 0, 0);
                __builtin_amdgcn_s_setprio(0);
            }
        }

        if (kt + 1 < NKT) {
            __builtin_amdgcn_s_barrier();       // all waves done reading buf[cur]
            if (kt + 2 < NKT) {
                STAGE_TILE(kt + 2, cur);
                asm volatile("s_waitcnt vmcnt(8)" ::: "memory");  // kt+1 landed; kt+2 in flight
            } else {
                asm volatile("s_waitcnt vmcnt(0)" ::: "memory");  // tail: drain
            }
            __builtin_amdgcn_s_barrier();       // kt+1 visible to all waves
        }
    }
#undef STAGE_TILE

    // epilogue
#pragma unroll
    for (int mi = 0; mi < 8; mi++) {
#pragma unroll
        for (int ni = 0; ni < 4; ni++) {
            const int row = m0 + wm * 128 + mi * 16 + lg * 4;
            const int col = n0 + wn * 64 + ni * 16 + lr;
            const float sc = (col < scale_cols) ? scale : 1.0f;
#pragma unroll
            for (int j = 0; j < 4; j++)
                C[(size_t)(row + j) * N + col] = f2b(acc[mi][ni][j] * sc);
        }
    }
}

// ------------- GEMM: C(MxN) = A(MxK,bf16) * BT(NxK,bf16)^T (128x128, m97-style) -------------
template <bool OUT_BF16>
__global__ __launch_bounds__(256) void gemm_bt(const ushort_t* __restrict__ A,
                                               const ushort_t* __restrict__ BT,
                                               void* __restrict__ C,
                                               int M, int N, int K,
                                               int scale_cols, float scale) {
    __shared__ __align__(16) ushort_t As2[128 * 32];
    __shared__ __align__(16) ushort_t Bs2[128 * 32];
    const int t = threadIdx.x;
    const int l = t & 63, w = t >> 6;
    const int wm = w >> 1, wn = w & 1;
    const int m0 = blockIdx.y * 128, n0 = blockIdx.x * 128;
    const int r1 = t >> 2, ko = (t & 3) * 8;

    f32x4 acc[4][4] = {};

    for (int k0 = 0; k0 < K; k0 += 32) {
        gload_lds16(A + (size_t)(m0 + r1) * K + k0 + ko,      &As2[(size_t)t * 8]);
        gload_lds16(A + (size_t)(m0 + 64 + r1) * K + k0 + ko, &As2[((size_t)t + 256) * 8]);
        gload_lds16(BT + (size_t)(n0 + r1) * K + k0 + ko,     &Bs2[(size_t)t * 8]);
        gload_lds16(BT + (size_t)(n0 + 64 + r1) * K + k0 + ko,&Bs2[((size_t)t + 256) * 8]);
        __syncthreads();

        bf16x8 af[4], bfr[4];
#pragma unroll
        for (int i = 0; i < 4; i++) {
            af[i]  = *(const bf16x8*)&As2[(wm * 64 + i * 16 + (l & 15)) * 32 + (l >> 4) * 8];
            bfr[i] = *(const bf16x8*)&Bs2[(wn * 64 + i * 16 + (l & 15)) * 32 + (l >> 4) * 8];
        }
#pragma unroll
        for (int mi = 0; mi < 4; mi++)
#pragma unroll
            for (int ni = 0; ni < 4; ni++)
                acc[mi][ni] = __builtin_amdgcn_mfma_f32_16x16x32_bf16(af[mi], bfr[ni], acc[mi][ni], 0, 0, 0);
        __syncthreads();
    }

#pragma unroll
    for (int mi = 0; mi < 4; mi++) {
#pragma unroll
        for (int ni = 0; ni < 4; ni++) {
            int row = m0 + wm * 64 + mi * 16 + ((l >> 4) << 2);
            int col = n0 + wn * 64 + ni * 16 + (l & 15);
            float sc = (col < scale_cols) ? scale : 1.0f;
#pragma unroll
            for (int j = 0; j < 4; j++) {
                float v = acc[mi][ni][j] * sc;
                if (OUT_BF16)
                    ((ushort_t*)C)[(size_t)(row + j) * N + col] = f2b(v);
                else
                    ((float*)C)[(size_t)(row + j) * N + col] = v;
            }
        }
    }
}

// ------------- flash attention v3: 8 waves x 16 q-rows, paired q-tiles, dbuf gload_lds -------------
__global__ __launch_bounds__(512, 1) void attn_fwd3(const ushort_t* __restrict__ qkvb,
                                                    const ushort_t* __restrict__ vT,
                                                    ushort_t* __restrict__ attnb) {
    __shared__ __align__(16) ushort_t Ks[2][64 * 128];   // [kv][d] swizzled, 16 KB each
    __shared__ __align__(16) ushort_t Vs[2][128 * 64];   // [d][kv] swizzled, 16 KB each
    __shared__ __align__(16) ushort_t Ps[8][16 * 64];    // per-wave P, 2 KB each

    const int t = threadIdx.x;
    const int l = t & 63, w = t >> 6;
    const int lr = l & 15, lg = l >> 4;
    const int pr = blockIdx.x, h = blockIdx.y, b = blockIdx.z;

    const ushort_t* kg = qkvb + (size_t)(b * SEQ) * QKVN + HID + h * HD;
    const ushort_t* vg = vT + (size_t)(b * NH + h) * HD * SEQ;

    char* PsB = (char*)Ps[w];
    const int pssz = ((lr & 7) ^ ((lr >> 3) << 1)) << 4;

    const int kcA = 2 * w, kcB = 2 * w + 1;
    const int krA = 8 * w + (l >> 4), krB = krA + 4;
    const int kcolA = ((l & 15) ^ (l >> 4)) << 3;
    const int kcolB = ((l & 15) ^ (4 + (l >> 4))) << 3;
    const int vrA = 16 * w + (l >> 3), vrB = vrA + 8;
    const int vcol = ((l & 7) ^ (l >> 3)) << 3;

    for (int seg = 0; seg < 2; seg++) {
        const int qt = (seg == 0) ? pr : 15 - pr;
        const int q0 = qt * QB;
        const int q0w = q0 + w * 16;
        const int NT = (q0 + QB) / KVB;

        bf16x8 qf[4];
        {
            const ushort_t* qb = qkvb + (size_t)(b * SEQ + q0w + lr) * QKVN + h * HD + lg * 8;
#pragma unroll
            for (int kc = 0; kc < 4; kc++) qf[kc] = *(const bf16x8*)(qb + kc * 32);
        }
        f32x4 o[8] = {};
        float m[4] = {-3e38f, -3e38f, -3e38f, -3e38f};
        float ls[4] = {0.f, 0.f, 0.f, 0.f};

        __syncthreads();
        gload_lds16(kg + (size_t)krA * QKVN + kcolA, &Ks[0][kcA * 512 + l * 8]);
        gload_lds16(kg + (size_t)krB * QKVN + kcolB, &Ks[0][kcB * 512 + l * 8]);
        gload_lds16(vg + (size_t)vrA * SEQ + vcol,   &Vs[0][kcA * 512 + l * 8]);
        gload_lds16(vg + (size_t)vrB * SEQ + vcol,   &Vs[0][kcB * 512 + l * 8]);

        for (int kt = 0; kt < NT; kt++) {
            const int kv0 = kt * KVB;
            __syncthreads();
            if (kt + 1 < NT) {
                const int nb = (kt + 1) & 1;
                const int nkv = kv0 + KVB;
                gload_lds16(kg + (size_t)(nkv + krA) * QKVN + kcolA, &Ks[nb][kcA * 512 + l * 8]);
                gload_lds16(kg + (size_t)(nkv + krB) * QKVN + kcolB, &Ks[nb][kcB * 512 + l * 8]);
                gload_lds16(vg + (size_t)vrA * SEQ + nkv + vcol,     &Vs[nb][kcA * 512 + l * 8]);
                gload_lds16(vg + (size_t)vrB * SEQ + nkv + vcol,     &Vs[nb][kcB * 512 + l * 8]);
            }
            if (kv0 > q0w + 15) continue;
            const char* KsB = (const char*)Ks[kt & 1];
            const char* VsB = (const char*)Vs[kt & 1];

            f32x4 s[4];
            const int rs = (lr & 7) << 4;
#pragma unroll
            for (int nf = 0; nf < 4; nf++) {
                const int r = nf * 16 + lr;
                s[nf] = (f32x4){0.f, 0.f, 0.f, 0.f};
#pragma unroll
                for (int kc = 0; kc < 4; kc++) {
                    bf16x8 kf = *(const bf16x8*)(KsB + r * 256 + ((kc * 64 + lg * 16) ^ rs));
                    s[nf] = __builtin_amdgcn_mfma_f32_16x16x32_bf16(qf[kc], kf, s[nf], 0, 0, 0);
                }
            }

            const bool diag = (kv0 + 63 > q0w);
            float tm[4];
#pragma unroll
            for (int j = 0; j < 4; j++) {
                if (diag) {
                    const int qpos = q0w + lg * 4 + j;
#pragma unroll
                    for (int nf = 0; nf < 4; nf++)
                        if (kv0 + nf * 16 + lr > qpos) s[nf][j] = -3e38f;
                }
                tm[j] = fmaxf(fmaxf(s[0][j], s[1][j]), fmaxf(s[2][j], s[3][j]));
#pragma unroll
                for (int mk = 1; mk < 16; mk <<= 1)
                    tm[j] = fmaxf(tm[j], __shfl_xor(tm[j], mk, 64));
            }

            float grow = fmaxf(fmaxf(tm[0] - m[0], tm[1] - m[1]),
                               fmaxf(tm[2] - m[2], tm[3] - m[3]));
            if (!__all(grow <= 8.0f)) {
#pragma unroll
                for (int j = 0; j < 4; j++) {
                    const float mn = fmaxf(m[j], tm[j]);
                    const float fac = exp2f((m[j] - mn) * 1.44269504f);
                    m[j] = mn; ls[j] *= fac;
#pragma unroll
                    for (int nf2 = 0; nf2 < 8; nf2++) o[nf2][j] *= fac;
                }
            }

#pragma unroll
            for (int j = 0; j < 4; j++) {
                const int row = lg * 4 + j;
                const int rsz = ((row & 7) ^ ((row >> 3) << 1)) << 4;
                float psum = 0.f;
#pragma unroll
                for (int nf = 0; nf < 4; nf++) {
                    float p = exp2f((s[nf][j] - m[j]) * 1.44269504f);
                    psum += p;
                    union { float f; unsigned u; } cv; cv.f = p;
                    *(ushort_t*)(PsB + row * 128 + ((nf * 32 + lr * 2) ^ rsz)) = (ushort_t)(cv.u >> 16);
                }
                ls[j] += psum;
            }

            bf16x8 pa0 = *(const bf16x8*)(PsB + lr * 128 + ((lg * 16) ^ pssz));
            bf16x8 pa1 = *(const bf16x8*)(PsB + lr * 128 + ((64 + lg * 16) ^ pssz));
#pragma unroll
            for (int nf2 = 0; nf2 < 8; nf2++) {
                const int vr2 = nf2 * 16 + lr;
                bf16x8 vb0 = *(const bf16x8*)(VsB + vr2 * 128 + ((lg * 16) ^ rs));
                bf16x8 vb1 = *(const bf16x8*)(VsB + vr2 * 128 + ((64 + lg * 16) ^ rs));
                o[nf2] = __builtin_amdgcn_mfma_f32_16x16x32_bf16(pa0, vb0, o[nf2], 0, 0, 0);
                o[nf2] = __builtin_amdgcn_mfma_f32_16x16x32_bf16(pa1, vb1, o[nf2], 0, 0, 0);
            }
        }

        float inv[4];
#pragma unroll
        for (int j = 0; j < 4; j++) {
            float sum = ls[j];
#pragma unroll
            for (int mk = 1; mk < 16; mk <<= 1) sum += __shfl_xor(sum, mk, 64);
            inv[j] = 1.0f / sum;
        }
        ushort_t* ob = attnb + (size_t)(b * SEQ + q0w) * HID + h * HD;
#pragma unroll
        for (int nf2 = 0; nf2 < 8; nf2++)
#pragma unroll
            for (int j = 0; j < 4; j++)
                ob[(size_t)(lg * 4 + j) * HID + nf2 * 16 + lr] = f2b(o[nf2][j] * inv[j]);
    }
}

extern "C" void kernel_launch(void* const* d_in, const int* in_sizes, int n_in,
                              void* d_out, int out_size, void* d_ws, size_t ws_size,
                              hipStream_t stream) {
    const float* x     = (const float*)d_in[0];
    const float* w_qkv = (const float*)d_in[1];
    const float* w_out = (const float*)d_in[2];
    float* out = (float*)d_out;

    char* ws = (char*)d_ws;
    ushort_t* xb    = (ushort_t*)(ws);                 // 4096x2048 bf16
    ushort_t* wqkvT = (ushort_t*)(ws + 16777216);      // 6144x2048 bf16
    ushort_t* woutT = (ushort_t*)(ws + 41943040);      // 2048x2048 bf16
    ushort_t* qkvb  = (ushort_t*)(ws + 50331648);      // 4096x6144 bf16
    ushort_t* vT    = (ushort_t*)(ws + 100663296);     // [b][h][d][s] bf16
    ushort_t* attnb = (ushort_t*)(ws + 117440512);     // 4096x2048 bf16

    const int M = 2 * SEQ;  // 4096

    castbf<<<(M * HID) / (256 * 8), 256, 0, stream>>>(x, xb, M * HID);
    transcast<<<dim3(QKVN / 32, HID / 32), 256, 0, stream>>>(w_qkv, wqkvT, HID, QKVN);
    transcast<<<dim3(HID / 32, HID / 32), 256, 0, stream>>>(w_out, woutT, HID, HID);

    // qkv = x @ w_qkv with Q pre-scaled; 256x256 deep-pipelined GEMM, 384 blocks
    gemm256<<<(M / 256) * (QKVN / 256), 512, 0, stream>>>(
        xb, wqkvT, qkvb, M, QKVN, HID, HID, 0.08838834764831845f);

    transV<<<dim3(SEQ / 32, HD / 32, 2 * NH), 256, 0, stream>>>(qkvb, vT);

    attn_fwd3<<<dim3(8, NH, 2), 512, 0, stream>>>(qkvb, vT, attnb);

    gemm_bt<false><<<dim3(HID / 128, M / 128), 256, 0, stream>>>(
        attnb, woutT, out, M, HID, HID, 0, 1.0f);
}